// Round 2
// baseline (190.443 us; speedup 1.0000x reference)
//
#include <hip/hip_runtime.h>
#include <stdint.h>

#define NHEADS 16
#define DHEAD 64
#define SEQ 2048
#define BATCH 2
#define NINF 1024
#define NOUTF 1024
#define N3 3072
#define MTOT 4096  // BATCH*SEQ

typedef unsigned short US;
typedef __attribute__((ext_vector_type(8))) short short8;
typedef __attribute__((ext_vector_type(4))) short short4v;
typedef __attribute__((ext_vector_type(4))) float f32x4;

__device__ inline US f2bf(float f) {
  union { float f; unsigned u; } v; v.f = f;
  unsigned r = v.u + 0x7fffu + ((v.u >> 16) & 1u);
  return (US)(r >> 16);
}

__device__ inline f32x4 mfma16(short8 a, short8 b, f32x4 c) {
  return __builtin_amdgcn_mfma_f32_16x16x32_bf16(a, b, c, 0, 0, 0);
}

__device__ inline f32x4 mfma16k16(short4v a, short4v b, f32x4 c) {
  return __builtin_amdgcn_mfma_f32_16x16x16bf16_1k(a, b, c, 0, 0, 0);
}

__device__ inline void async16(const US* g, US* l) {
  __builtin_amdgcn_global_load_lds(
      (const __attribute__((address_space(1))) unsigned int*)g,
      (__attribute__((address_space(3))) unsigned int*)l, 16, 0, 0);
}

// fp32 -> bf16, 4 elements/thread
__global__ void k_convert(const float* __restrict__ src, US* __restrict__ dst, int n4) {
  int i = blockIdx.x * blockDim.x + threadIdx.x;
  if (i >= n4) return;
  float4 v = ((const float4*)src)[i];
  ushort4 o;
  o.x = f2bf(v.x); o.y = f2bf(v.y); o.z = f2bf(v.z); o.w = f2bf(v.w);
  ((ushort4*)dst)[i] = o;
}

// merged weight transpose: Wqkv [1024][3072] and Wff [1024][1024] -> bf16 [C][1024]
__global__ void k_wtrans(const float* __restrict__ Wqkv, const float* __restrict__ Wff,
                         US* __restrict__ dq, US* __restrict__ df) {
  __shared__ float tile[32][33];
  int bxi = blockIdx.x;
  const float* src; US* dst; int C;
  if (bxi < 96) { src = Wqkv; dst = dq; C = N3; }
  else          { src = Wff;  dst = df; C = NOUTF; bxi -= 96; }
  int bx = bxi * 32, by = blockIdx.y * 32;
  int tx = threadIdx.x, ty = threadIdx.y;
  for (int i = 0; i < 32; i += 8)
    tile[ty + i][tx] = src[(size_t)(by + ty + i) * C + bx + tx];
  __syncthreads();
  for (int i = 0; i < 32; i += 8)
    dst[(size_t)(bx + ty + i) * 1024 + by + tx] = f2bf(tile[tx][ty + i]);
}

// per-bh bf16 transpose: vbuf [bh][2048][64] -> vtbuf [bh][64][2048]
__global__ void k_vtrans(const US* __restrict__ src, US* __restrict__ dst) {
  __shared__ US tile[32][33];
  int bh = blockIdx.z;
  int bx = blockIdx.x * 32;  // d
  int by = blockIdx.y * 32;  // s
  int tx = threadIdx.x, ty = threadIdx.y;
  const US* s0 = src + (size_t)bh * SEQ * DHEAD;
  US* d0 = dst + (size_t)bh * DHEAD * SEQ;
  for (int i = 0; i < 32; i += 8)
    tile[ty + i][tx] = s0[(size_t)(by + ty + i) * DHEAD + bx + tx];
  __syncthreads();
  for (int i = 0; i < 32; i += 8)
    d0[(size_t)(bx + ty + i) * SEQ + by + tx] = tile[tx][ty + i];
}

// ---------------- qkv GEMM: 128x128 tile, m97 structure ----------------
// Q is pre-scaled by log2(e)/sqrt(DHEAD) so attention scores are directly
// exp2 exponents (deletes one v_mul per score in k_attn).
__global__ __launch_bounds__(256) void k_gemm_qkv(
    const US* __restrict__ A,   // [MTOT][NINF]
    const US* __restrict__ Bt,  // [N3][NINF]
    US* __restrict__ qbuf, US* __restrict__ kbuf, US* __restrict__ vbuf) {
  __shared__ US As[128 * 32];
  __shared__ US Bs[128 * 32];
  int tid = threadIdx.x;
  int wave = tid >> 6, lane = tid & 63, lm = lane & 15, lk = lane >> 4;
  int wm = wave >> 1, wn = wave & 1;
  int mbase = blockIdx.y * 128, nbase = blockIdx.x * 128;

  f32x4 acc[4][4];
#pragma unroll
  for (int i = 0; i < 4; ++i)
#pragma unroll
    for (int j = 0; j < 4; ++j) acc[i][j] = (f32x4){0.f, 0.f, 0.f, 0.f};

  const US* ga = A + (size_t)(mbase + (tid >> 2)) * NINF + (tid & 3) * 8;
  const US* gb = Bt + (size_t)(nbase + (tid >> 2)) * NINF + (tid & 3) * 8;
  US* la = As + tid * 8;
  US* lb = Bs + tid * 8;

  for (int kt = 0; kt < NINF / 32; ++kt) {
    int ko = kt * 32;
    async16(ga + ko, la);
    async16(ga + ko + (size_t)64 * NINF, la + 64 * 32);
    async16(gb + ko, lb);
    async16(gb + ko + (size_t)64 * NINF, lb + 64 * 32);
    __syncthreads();
    short8 a[4], b[4];
#pragma unroll
    for (int i = 0; i < 4; ++i)
      a[i] = *(const short8*)(As + (wm * 64 + i * 16 + lm) * 32 + lk * 8);
#pragma unroll
    for (int j = 0; j < 4; ++j)
      b[j] = *(const short8*)(Bs + (wn * 64 + j * 16 + lm) * 32 + lk * 8);
#pragma unroll
    for (int i = 0; i < 4; ++i)
#pragma unroll
      for (int j = 0; j < 4; ++j) acc[i][j] = mfma16(a[i], b[j], acc[i][j]);
    __syncthreads();
  }

  int which = nbase >> 10;  // 0=q 1=k 2=v (uniform per block)
  US* dsts = (which == 0) ? qbuf : (which == 1) ? kbuf : vbuf;
  float sc = (which == 0) ? 0.18033688011112042f : 1.f;  // log2(e)/8 folded into Q
#pragma unroll
  for (int j = 0; j < 4; ++j) {
    int col = nbase + wn * 64 + j * 16 + lm;
    int hh = (col & 1023) >> 6;
    int d = col & 63;
#pragma unroll
    for (int i = 0; i < 4; ++i) {
#pragma unroll
      for (int r = 0; r < 4; ++r) {
        int row = mbase + wm * 64 + i * 16 + lk * 4 + r;
        int bb = row >> 11;
        int s = row & (SEQ - 1);
        int bh = bb * NHEADS + hh;
        dsts[((size_t)bh * SEQ + s) * DHEAD + d] = f2bf(acc[i][j][r] * sc);
      }
    }
  }
}

// ---------------- attention v7: paired strips + dbuf counted-vmcnt ----------------
// v6 body kept verbatim (verified): 64-key LDS tiles, S^T=K*Q^T, Q pre-scaled,
// rowsums via ones-MFMA, P bf16 pack via +0x8000 bias + v_perm_b32.
// v7 (attacks latency + imbalance, the measured bottleneck):
//  - strips s and 31-s paired per block -> constant 33 tile-bodies/block,
//    512 perfectly-balanced blocks (2/CU), K/V staging shared by both strips
//  - double-buffered K/V LDS (32 KB) with raw s_barrier + counted
//    s_waitcnt vmcnt(4): tile t+2's loads fly during tile t+1's compute,
//    vmcnt never drains to 0 in the main loop (T3/T4-lite, depth 2)
// Resubmitted unchanged after infra-level container failure (audited: no
// conditional barriers, vmcnt wait precedes barrier, all bounds in range).
__global__ __launch_bounds__(256) void k_attn(
    const US* __restrict__ qbuf, const US* __restrict__ kbuf,
    const US* __restrict__ vtbuf, US* __restrict__ ctx) {
  __shared__ US Ks[2][64 * 64];
  __shared__ US Vs[2][64 * 64];
  int tid = threadIdx.x;
  int w = tid >> 6, lane = tid & 63;
  int lm = lane & 15, lk = lane >> 4;
  int bl = blockIdx.x;          // 512 blocks
  int xcd = bl & 7, g = bl >> 3;  // g 0..63
  int bh = (g & 3) * 8 + xcd;   // 4 bh per XCD -> working set ~2MB < 4MB L2
  int pr = g >> 2;              // pair index 0..15
  int sA = pr;                  // short strip
  int sB = 31 - pr;             // long strip
  int nt = sB + 1;              // tiles staged (>= 17)

  const US* kbase = kbuf + (size_t)bh * SEQ * DHEAD;
  const US* vtb = vtbuf + (size_t)bh * DHEAD * SEQ;
  const US* qrA = qbuf + ((size_t)bh * SEQ + sA * 64 + w * 16 + lm) * DHEAD + lk * 8;
  const US* qrB = qbuf + ((size_t)bh * SEQ + sB * 64 + w * 16 + lm) * DHEAD + lk * 8;
  short8 qA0 = *(const short8*)(qrA);
  short8 qA1 = *(const short8*)(qrA + 32);
  short8 qB0 = *(const short8*)(qrB);
  short8 qB1 = *(const short8*)(qrB + 32);

  // staging: 16 async16 units (8 K + 8 V), 4 per wave, source-side XOR swizzle
  int swz = ((lane & 7) ^ (lane >> 3)) * 8;
  const US* gsrc[4];
  US* ldst[4];
  int step[4];
#pragma unroll
  for (int j = 0; j < 4; ++j) {
    int u = w + 4 * j;
    if (u < 8) {
      gsrc[j] = kbase + (size_t)(u * 8 + (lane >> 3)) * DHEAD + swz;
      ldst[j] = &Ks[0][0] + u * 512 + lane * 8;
      step[j] = 64 * DHEAD;
    } else {
      int i = u - 8;
      gsrc[j] = vtb + (size_t)(i * 8 + (lane >> 3)) * SEQ + swz;
      ldst[j] = &Vs[0][0] + i * 512 + lane * 8;
      step[j] = 64;
    }
  }

  // fragment-read offsets (bytes), swizzle-corrected
  int xorv = lm & 7;
  int ck0 = ((lk) ^ xorv) * 16;
  int ck1 = ((4 + lk) ^ xorv) * 16;
  int cv[4];
#pragma unroll
  for (int kg = 0; kg < 4; ++kg)
    cv[kg] = (((kg * 2 + (lk >> 1)) ^ xorv) * 16) + (lk & 1) * 8;

  f32x4 oA[4], oB[4];
#pragma unroll
  for (int dg = 0; dg < 4; ++dg) {
    oA[dg] = (f32x4){0.f, 0.f, 0.f, 0.f};
    oB[dg] = (f32x4){0.f, 0.f, 0.f, 0.f};
  }
  f32x4 lA = (f32x4){0.f, 0.f, 0.f, 0.f};
  f32x4 lB = (f32x4){0.f, 0.f, 0.f, 0.f};
  const short4v kones = {(short)0x3F80, (short)0x3F80, (short)0x3F80, (short)0x3F80};

  auto body = [&](const char* Kc, const char* Vc, int kg, bool dm,
                  short8 q0, short8 q1, f32x4* o, f32x4& ls) {
    const char* kr = Kc + (kg * 16 + lm) * 128;
    short8 ka0 = *(const short8*)(kr + ck0);
    short8 ka1 = *(const short8*)(kr + ck1);
    f32x4 st = (f32x4){0.f, 0.f, 0.f, 0.f};
    st = mfma16(ka0, q0, st);
    st = mfma16(ka1, q1, st);
    uint32_t ue[4];
#pragma unroll
    for (int r = 0; r < 4; ++r) {
      float v = st[r];                       // already in log2 domain (Q pre-scaled)
      if (dm && (lk * 4 + r > lm)) v = -INFINITY;
      union { float f; uint32_t u; } cv2;
      cv2.f = exp2f(v);
      ue[r] = cv2.u + 0x8000u;               // bf16 bias-round; -inf path -> 0x8000 -> +0
    }
    union { short4v s4; uint32_t u[2]; } pk;
    pk.u[0] = __builtin_amdgcn_perm(ue[1], ue[0], 0x07060302u);
    pk.u[1] = __builtin_amdgcn_perm(ue[3], ue[2], 0x07060302u);
    ls = mfma16k16(kones, pk.s4, ls);        // row-sums on the MFMA pipe
    const char* vr = Vc + lm * 128 + cv[kg];
#pragma unroll
    for (int dg = 0; dg < 4; ++dg) {
      short4v va = *(const short4v*)(vr + dg * 2048);
      o[dg] = mfma16k16(va, pk.s4, o[dg]);
    }
  };

  auto doTile = [&](int t) {
    const char* Kc = (const char*)Ks + (t & 1) * 8192;
    const char* Vc = (const char*)Vs + (t & 1) * 8192;
    // long strip B: active for all tiles, diagonal at t == sB (last tile)
    if (t < sB) {
#pragma unroll
      for (int kg = 0; kg < 4; ++kg) body(Kc, Vc, kg, false, qB0, qB1, oB, lB);
    } else {
      for (int kg = 0; kg < w; ++kg) body(Kc, Vc, kg, false, qB0, qB1, oB, lB);
      body(Kc, Vc, w, true, qB0, qB1, oB, lB);
    }
    // short strip A: active for t <= sA, diagonal at t == sA
    if (t < sA) {
#pragma unroll
      for (int kg = 0; kg < 4; ++kg) body(Kc, Vc, kg, false, qA0, qA1, oA, lA);
    } else if (t == sA) {
      for (int kg = 0; kg < w; ++kg) body(Kc, Vc, kg, false, qA0, qA1, oA, lA);
      body(Kc, Vc, w, true, qA0, qA1, oA, lA);
    }
  };

  // prologue: tile0 -> buf0, tile1 -> buf1 (nt >= 17 always)
#pragma unroll
  for (int j = 0; j < 4; ++j) { async16(gsrc[j], ldst[j]); gsrc[j] += step[j]; }
#pragma unroll
  for (int j = 0; j < 4; ++j) { async16(gsrc[j], ldst[j] + 4096); gsrc[j] += step[j]; }

  for (int t = 0; t < nt; ++t) {
    if (t + 1 < nt) asm volatile("s_waitcnt vmcnt(4)" ::: "memory");
    else            asm volatile("s_waitcnt vmcnt(0)" ::: "memory");
    __builtin_amdgcn_s_barrier();
    asm volatile("" ::: "memory");
    doTile(t);
    asm volatile("" ::: "memory");
    __builtin_amdgcn_s_barrier();
    asm volatile("" ::: "memory");
    if (t + 2 < nt) {
#pragma unroll
      for (int j = 0; j < 4; ++j) {
        async16(gsrc[j], ldst[j] + (t & 1) * 4096);
        gsrc[j] += step[j];
      }
    }
  }

  // lacc[*] = rowsum for q-row lm (identical across regs/lk groups)
  float invA = 1.f / lA[0];
  float invB = 1.f / lB[0];

  US* crowA = ctx + ((size_t)(bh >> 4) * SEQ + sA * 64 + w * 16 + lm) * NOUTF + (bh & 15) * DHEAD;
  US* crowB = ctx + ((size_t)(bh >> 4) * SEQ + sB * 64 + w * 16 + lm) * NOUTF + (bh & 15) * DHEAD;
#pragma unroll
  for (int dg = 0; dg < 4; ++dg) {
    union { short4v s4; uint32_t u[2]; } pk;
    pk.u[0] = (uint32_t)f2bf(oA[dg][0] * invA) | ((uint32_t)f2bf(oA[dg][1] * invA) << 16);
    pk.u[1] = (uint32_t)f2bf(oA[dg][2] * invA) | ((uint32_t)f2bf(oA[dg][3] * invA) << 16);
    *(short4v*)(crowA + dg * 16 + lk * 4) = pk.s4;
    pk.u[0] = (uint32_t)f2bf(oB[dg][0] * invB) | ((uint32_t)f2bf(oB[dg][1] * invB) << 16);
    pk.u[1] = (uint32_t)f2bf(oB[dg][2] * invB) | ((uint32_t)f2bf(oB[dg][3] * invB) << 16);
    *(short4v*)(crowB + dg * 16 + lk * 4) = pk.s4;
  }
}

// ---------------- out GEMM: 128x64 tile, fused bias, fp32 out ------
__global__ __launch_bounds__(256) void k_gemm_out(
    const US* __restrict__ A, const US* __restrict__ Bt,
    const float* __restrict__ bias, float* __restrict__ out) {
  __shared__ US As[128 * 32];
  __shared__ US Bs[64 * 32];
  int tid = threadIdx.x;
  int wave = tid >> 6, lane = tid & 63, lm = lane & 15, lk = lane >> 4;
  int mbase = blockIdx.y * 128, nbase = blockIdx.x * 64;

  f32x4 acc[2][4];
#pragma unroll
  for (int i = 0; i < 2; ++i)
#pragma unroll
    for (int j = 0; j < 4; ++j) acc[i][j] = (f32x4){0.f, 0.f, 0.f, 0.f};

  const US* ga = A + (size_t)(mbase + (tid >> 2)) * NOUTF + (tid & 3) * 8;
  const US* gb = Bt + (size_t)(nbase + (tid >> 2)) * NOUTF + (tid & 3) * 8;
  US* la = As + tid * 8;
  US* lb = Bs + tid * 8;

  for (int kt = 0; kt < NOUTF / 32; ++kt) {
    int ko = kt * 32;
    async16(ga + ko, la);
    async16(ga + ko + (size_t)64 * NOUTF, la + 64 * 32);
    async16(gb + ko, lb);
    __syncthreads();
    short8 a[2], b[4];
#pragma unroll
    for (int i = 0; i < 2; ++i)
      a[i] = *(const short8*)(As + (wave * 32 + i * 16 + lm) * 32 + lk * 8);
#pragma unroll
    for (int j = 0; j < 4; ++j)
      b[j] = *(const short8*)(Bs + (j * 16 + lm) * 32 + lk * 8);
#pragma unroll
    for (int i = 0; i < 2; ++i)
#pragma unroll
      for (int j = 0; j < 4; ++j) acc[i][j] = mfma16(a[i], b[j], acc[i][j]);
    __syncthreads();
  }

#pragma unroll
  for (int j = 0; j < 4; ++j) {
    int col = nbase + j * 16 + lm;
    float bv = bias[col];
#pragma unroll
    for (int i = 0; i < 2; ++i)
#pragma unroll
      for (int r = 0; r < 4; ++r) {
        int row = mbase + wave * 32 + i * 16 + lk * 4 + r;
        out[(size_t)row * NOUTF + col] = acc[i][j][r] + bv;
      }
  }
}

extern "C" void kernel_launch(void* const* d_in, const int* in_sizes, int n_in,
                              void* d_out, int out_size, void* d_ws, size_t ws_size,
                              hipStream_t stream) {
  const float* y    = (const float*)d_in[0];
  const float* Wqkv = (const float*)d_in[1];
  const float* Wff  = (const float*)d_in[2];
  const float* bff  = (const float*)d_in[3];
  float* out = (float*)d_out;

  char* ws = (char*)d_ws;
  US* ybf   = (US*)(ws);                 // [0,8M)  y bf16; dead after qkv
  US* ctx   = (US*)(ws);                 // [0,8M)  reuse for ctx
  US* wqkvt = (US*)(ws + (8u << 20));    // [8,14M)
  US* wfft  = (US*)(ws + (14u << 20));   // [14,16M)
  US* qbuf  = (US*)(ws + (16u << 20));   // [16,24M)
  US* kbuf  = (US*)(ws + (24u << 20));   // [24,32M)
  US* vbuf  = (US*)(ws + (32u << 20));   // [32,40M) dead after vtrans
  US* vtbuf = (US*)(ws + (40u << 20));   // [40,48M)

  k_convert<<<MTOT * NINF / 4 / 256, 256, 0, stream>>>(y, ybf, MTOT * NINF / 4);
  k_wtrans<<<dim3(128, 32), dim3(32, 8), 0, stream>>>(Wqkv, Wff, wqkvt, wfft);
  k_gemm_qkv<<<dim3(N3 / 128, MTOT / 128), 256, 0, stream>>>(ybf, wqkvt, qbuf, kbuf, vbuf);
  k_vtrans<<<dim3(DHEAD / 32, SEQ / 32, BATCH * NHEADS), dim3(32, 8), 0, stream>>>(vbuf, vtbuf);
  k_attn<<<dim3(512), 256, 0, stream>>>(qbuf, kbuf, vtbuf, ctx);
  k_gemm_out<<<dim3(NOUTF / 64, MTOT / 128), 256, 0, stream>>>(ctx, wfft, bff, out);
}

// Round 3
// 184.062 us; speedup vs baseline: 1.0347x; 1.0347x over previous
//
#include <hip/hip_runtime.h>
#include <stdint.h>

#define NHEADS 16
#define DHEAD 64
#define SEQ 2048
#define BATCH 2
#define NINF 1024
#define NOUTF 1024
#define N3 3072
#define MTOT 4096  // BATCH*SEQ

typedef unsigned short US;
typedef __attribute__((ext_vector_type(8))) short short8;
typedef __attribute__((ext_vector_type(4))) short short4v;
typedef __attribute__((ext_vector_type(4))) float f32x4;

__device__ inline US f2bf(float f) {
  union { float f; unsigned u; } v; v.f = f;
  unsigned r = v.u + 0x7fffu + ((v.u >> 16) & 1u);
  return (US)(r >> 16);
}

__device__ inline f32x4 mfma16(short8 a, short8 b, f32x4 c) {
  return __builtin_amdgcn_mfma_f32_16x16x32_bf16(a, b, c, 0, 0, 0);
}

__device__ inline f32x4 mfma16k16(short4v a, short4v b, f32x4 c) {
  return __builtin_amdgcn_mfma_f32_16x16x16bf16_1k(a, b, c, 0, 0, 0);
}

__device__ inline void async16(const US* g, US* l) {
  __builtin_amdgcn_global_load_lds(
      (const __attribute__((address_space(1))) unsigned int*)g,
      (__attribute__((address_space(3))) unsigned int*)l, 16, 0, 0);
}

// fp32 -> bf16, 4 elements/thread
__global__ void k_convert(const float* __restrict__ src, US* __restrict__ dst, int n4) {
  int i = blockIdx.x * blockDim.x + threadIdx.x;
  if (i >= n4) return;
  float4 v = ((const float4*)src)[i];
  ushort4 o;
  o.x = f2bf(v.x); o.y = f2bf(v.y); o.z = f2bf(v.z); o.w = f2bf(v.w);
  ((ushort4*)dst)[i] = o;
}

// merged weight transpose: Wqkv [1024][3072] and Wff [1024][1024] -> bf16 [C][1024]
__global__ void k_wtrans(const float* __restrict__ Wqkv, const float* __restrict__ Wff,
                         US* __restrict__ dq, US* __restrict__ df) {
  __shared__ float tile[32][33];
  int bxi = blockIdx.x;
  const float* src; US* dst; int C;
  if (bxi < 96) { src = Wqkv; dst = dq; C = N3; }
  else          { src = Wff;  dst = df; C = NOUTF; bxi -= 96; }
  int bx = bxi * 32, by = blockIdx.y * 32;
  int tx = threadIdx.x, ty = threadIdx.y;
  for (int i = 0; i < 32; i += 8)
    tile[ty + i][tx] = src[(size_t)(by + ty + i) * C + bx + tx];
  __syncthreads();
  for (int i = 0; i < 32; i += 8)
    dst[(size_t)(bx + ty + i) * 1024 + by + tx] = f2bf(tile[tx][ty + i]);
}

// per-bh bf16 transpose: vbuf [bh][2048][64] -> vtbuf [bh][64][2048]
__global__ void k_vtrans(const US* __restrict__ src, US* __restrict__ dst) {
  __shared__ US tile[32][33];
  int bh = blockIdx.z;
  int bx = blockIdx.x * 32;  // d
  int by = blockIdx.y * 32;  // s
  int tx = threadIdx.x, ty = threadIdx.y;
  const US* s0 = src + (size_t)bh * SEQ * DHEAD;
  US* d0 = dst + (size_t)bh * DHEAD * SEQ;
  for (int i = 0; i < 32; i += 8)
    tile[ty + i][tx] = s0[(size_t)(by + ty + i) * DHEAD + bx + tx];
  __syncthreads();
  for (int i = 0; i < 32; i += 8)
    d0[(size_t)(bx + ty + i) * SEQ + by + tx] = tile[tx][ty + i];
}

// ---------------- qkv GEMM: 128x128 tile, m97 structure ----------------
// Q is pre-scaled by log2(e)/sqrt(DHEAD) so attention scores are directly
// exp2 exponents (deletes one v_mul per score in k_attn).
__global__ __launch_bounds__(256) void k_gemm_qkv(
    const US* __restrict__ A,   // [MTOT][NINF]
    const US* __restrict__ Bt,  // [N3][NINF]
    US* __restrict__ qbuf, US* __restrict__ kbuf, US* __restrict__ vbuf) {
  __shared__ US As[128 * 32];
  __shared__ US Bs[128 * 32];
  int tid = threadIdx.x;
  int wave = tid >> 6, lane = tid & 63, lm = lane & 15, lk = lane >> 4;
  int wm = wave >> 1, wn = wave & 1;
  int mbase = blockIdx.y * 128, nbase = blockIdx.x * 128;

  f32x4 acc[4][4];
#pragma unroll
  for (int i = 0; i < 4; ++i)
#pragma unroll
    for (int j = 0; j < 4; ++j) acc[i][j] = (f32x4){0.f, 0.f, 0.f, 0.f};

  const US* ga = A + (size_t)(mbase + (tid >> 2)) * NINF + (tid & 3) * 8;
  const US* gb = Bt + (size_t)(nbase + (tid >> 2)) * NINF + (tid & 3) * 8;
  US* la = As + tid * 8;
  US* lb = Bs + tid * 8;

  for (int kt = 0; kt < NINF / 32; ++kt) {
    int ko = kt * 32;
    async16(ga + ko, la);
    async16(ga + ko + (size_t)64 * NINF, la + 64 * 32);
    async16(gb + ko, lb);
    async16(gb + ko + (size_t)64 * NINF, lb + 64 * 32);
    __syncthreads();
    short8 a[4], b[4];
#pragma unroll
    for (int i = 0; i < 4; ++i)
      a[i] = *(const short8*)(As + (wm * 64 + i * 16 + lm) * 32 + lk * 8);
#pragma unroll
    for (int j = 0; j < 4; ++j)
      b[j] = *(const short8*)(Bs + (wn * 64 + j * 16 + lm) * 32 + lk * 8);
#pragma unroll
    for (int i = 0; i < 4; ++i)
#pragma unroll
      for (int j = 0; j < 4; ++j) acc[i][j] = mfma16(a[i], b[j], acc[i][j]);
    __syncthreads();
  }

  int which = nbase >> 10;  // 0=q 1=k 2=v (uniform per block)
  US* dsts = (which == 0) ? qbuf : (which == 1) ? kbuf : vbuf;
  float sc = (which == 0) ? 0.18033688011112042f : 1.f;  // log2(e)/8 folded into Q
#pragma unroll
  for (int j = 0; j < 4; ++j) {
    int col = nbase + wn * 64 + j * 16 + lm;
    int hh = (col & 1023) >> 6;
    int d = col & 63;
#pragma unroll
    for (int i = 0; i < 4; ++i) {
#pragma unroll
      for (int r = 0; r < 4; ++r) {
        int row = mbase + wm * 64 + i * 16 + lk * 4 + r;
        int bb = row >> 11;
        int s = row & (SEQ - 1);
        int bh = bb * NHEADS + hh;
        dsts[((size_t)bh * SEQ + s) * DHEAD + d] = f2bf(acc[i][j][r] * sc);
      }
    }
  }
}

// ---------------- attention v8: v6 structure + balanced rounds + dbuf ----------------
// v6 body verbatim (verified): block = 64-row strip, 64-key LDS tiles, S^T=K*Q^T,
// Q pre-scaled, rowsums via ones-MFMA, P bf16 pack via +0x8000 bias + v_perm_b32.
// v7 post-mortem: in-block strip pairing halved blocks/CU (2 waves/SIMD) and
// REGRESSED 49.9->57.5us -- TLP was what hid the per-body dep chain.
// v8 keeps 1024 blocks (4/CU, 16 waves/CU) and instead balances across
// dispatch rounds: blocks reach CUs round-robin in 4 rounds of 256; map
// round->strip so every CU's 4 strips sum to 66 tiles:
//   round 0: s=31-k (heavy), round 1: s=k, round 2: s=23-k, round 3: s=8+k
//   (32-k)+(k+1)+(24-k)+(9+k) = 66 for all k.
// Keeps v7's audited depth-2 double buffer + counted s_waitcnt vmcnt(4)
// (loads for tile t+2 fly during tile t+1's compute; never drains to 0).
__global__ __launch_bounds__(256) void k_attn(
    const US* __restrict__ qbuf, const US* __restrict__ kbuf,
    const US* __restrict__ vtbuf, US* __restrict__ ctx) {
  __shared__ US Ks[2][64 * 64];
  __shared__ US Vs[2][64 * 64];
  int tid = threadIdx.x;
  int w = tid >> 6, lane = tid & 63;
  int lm = lane & 15, lk = lane >> 4;
  int bl = blockIdx.x;            // 1024 blocks
  int xcd = bl & 7, g = bl >> 3;  // g 0..127
  int bh = (g & 3) * 8 + xcd;     // 4 bh per XCD -> working set ~2MB < 4MB L2
  int q4 = g >> 2;                // 0..31; dispatch round = q4>>3, k = q4&7
  int rr = q4 >> 3, qq = q4 & 7;
  int s = (rr == 0) ? 31 - qq : (rr == 1) ? qq : (rr == 2) ? 23 - qq : 8 + qq;
  int qb = s * 64 + w * 16;
  int nt = s + 1;                 // 64-key tiles (can be 1)

  const US* kbase = kbuf + (size_t)bh * SEQ * DHEAD;
  const US* vtb = vtbuf + (size_t)bh * DHEAD * SEQ;
  const US* qr = qbuf + ((size_t)bh * SEQ + qb + lm) * DHEAD + lk * 8;
  short8 qf0 = *(const short8*)(qr);
  short8 qf1 = *(const short8*)(qr + 32);

  // staging: 16 async16 units (8 K + 8 V), 4 per wave, source-side XOR swizzle
  int swz = ((lane & 7) ^ (lane >> 3)) * 8;
  const US* gsrc[4];
  US* ldst[4];
  int step[4];
#pragma unroll
  for (int j = 0; j < 4; ++j) {
    int u = w + 4 * j;
    if (u < 8) {
      gsrc[j] = kbase + (size_t)(u * 8 + (lane >> 3)) * DHEAD + swz;
      ldst[j] = &Ks[0][0] + u * 512 + lane * 8;
      step[j] = 64 * DHEAD;
    } else {
      int i = u - 8;
      gsrc[j] = vtb + (size_t)(i * 8 + (lane >> 3)) * SEQ + swz;
      ldst[j] = &Vs[0][0] + i * 512 + lane * 8;
      step[j] = 64;
    }
  }

  // fragment-read offsets (bytes), swizzle-corrected
  int xorv = lm & 7;
  int ck0 = ((lk) ^ xorv) * 16;
  int ck1 = ((4 + lk) ^ xorv) * 16;
  int cv[4];
#pragma unroll
  for (int kg = 0; kg < 4; ++kg)
    cv[kg] = (((kg * 2 + (lk >> 1)) ^ xorv) * 16) + (lk & 1) * 8;

  f32x4 o[4];
#pragma unroll
  for (int dg = 0; dg < 4; ++dg) o[dg] = (f32x4){0.f, 0.f, 0.f, 0.f};
  f32x4 lacc = (f32x4){0.f, 0.f, 0.f, 0.f};
  const short4v kones = {(short)0x3F80, (short)0x3F80, (short)0x3F80, (short)0x3F80};

  auto body = [&](const char* Kc, const char* Vc, int kg, bool dm) {
    const char* kr = Kc + (kg * 16 + lm) * 128;
    short8 ka0 = *(const short8*)(kr + ck0);
    short8 ka1 = *(const short8*)(kr + ck1);
    f32x4 st = (f32x4){0.f, 0.f, 0.f, 0.f};
    st = mfma16(ka0, qf0, st);
    st = mfma16(ka1, qf1, st);
    uint32_t ue[4];
#pragma unroll
    for (int r = 0; r < 4; ++r) {
      float v = st[r];                       // already in log2 domain (Q pre-scaled)
      if (dm && (lk * 4 + r > lm)) v = -INFINITY;
      union { float f; uint32_t u; } cv2;
      cv2.f = exp2f(v);
      ue[r] = cv2.u + 0x8000u;               // bf16 bias-round; -inf path -> 0x8000 -> +0
    }
    union { short4v s4; uint32_t u[2]; } pk;
    pk.u[0] = __builtin_amdgcn_perm(ue[1], ue[0], 0x07060302u);
    pk.u[1] = __builtin_amdgcn_perm(ue[3], ue[2], 0x07060302u);
    lacc = mfma16k16(kones, pk.s4, lacc);    // row-sums on the MFMA pipe
    const char* vr = Vc + lm * 128 + cv[kg];
#pragma unroll
    for (int dg = 0; dg < 4; ++dg) {
      short4v va = *(const short4v*)(vr + dg * 2048);
      o[dg] = mfma16k16(va, pk.s4, o[dg]);
    }
  };

  // prologue: tile0 -> buf0, (tile1 -> buf1 if it exists)
#pragma unroll
  for (int j = 0; j < 4; ++j) { async16(gsrc[j], ldst[j]); gsrc[j] += step[j]; }
  if (nt > 1) {
#pragma unroll
    for (int j = 0; j < 4; ++j) { async16(gsrc[j], ldst[j] + 4096); gsrc[j] += step[j]; }
  }

  for (int t = 0; t < nt; ++t) {
    if (t + 1 < nt) asm volatile("s_waitcnt vmcnt(4)" ::: "memory");
    else            asm volatile("s_waitcnt vmcnt(0)" ::: "memory");
    __builtin_amdgcn_s_barrier();
    asm volatile("" ::: "memory");
    const char* Kc = (const char*)Ks + (t & 1) * 8192;
    const char* Vc = (const char*)Vs + (t & 1) * 8192;
    if (t < s) {
#pragma unroll
      for (int kg = 0; kg < 4; ++kg) body(Kc, Vc, kg, false);
    } else {
      // diagonal tile: kg > w fully masked, kg == w partially
      for (int kg = 0; kg < w; ++kg) body(Kc, Vc, kg, false);
      body(Kc, Vc, w, true);
    }
    asm volatile("" ::: "memory");
    __builtin_amdgcn_s_barrier();
    asm volatile("" ::: "memory");
    if (t + 2 < nt) {
#pragma unroll
      for (int j = 0; j < 4; ++j) {
        async16(gsrc[j], ldst[j] + (t & 1) * 4096);
        gsrc[j] += step[j];
      }
    }
  }

  // lacc[*] = rowsum for q-row lm (identical across regs/lk groups)
  float inv = 1.f / lacc[0];

  US* crow = ctx + ((size_t)(bh >> 4) * SEQ + qb + lm) * NOUTF + (bh & 15) * DHEAD;
#pragma unroll
  for (int dg = 0; dg < 4; ++dg) {
    union { short4v s4; uint32_t u[2]; } pk;
    pk.u[0] = (uint32_t)f2bf(o[dg][0] * inv) | ((uint32_t)f2bf(o[dg][1] * inv) << 16);
    pk.u[1] = (uint32_t)f2bf(o[dg][2] * inv) | ((uint32_t)f2bf(o[dg][3] * inv) << 16);
    *(short4v*)(crow + dg * 16 + lk * 4) = pk.s4;
  }
}

// ---------------- out GEMM: 128x64 tile, fused bias, fp32 out ------
__global__ __launch_bounds__(256) void k_gemm_out(
    const US* __restrict__ A, const US* __restrict__ Bt,
    const float* __restrict__ bias, float* __restrict__ out) {
  __shared__ US As[128 * 32];
  __shared__ US Bs[64 * 32];
  int tid = threadIdx.x;
  int wave = tid >> 6, lane = tid & 63, lm = lane & 15, lk = lane >> 4;
  int mbase = blockIdx.y * 128, nbase = blockIdx.x * 64;

  f32x4 acc[2][4];
#pragma unroll
  for (int i = 0; i < 2; ++i)
#pragma unroll
    for (int j = 0; j < 4; ++j) acc[i][j] = (f32x4){0.f, 0.f, 0.f, 0.f};

  const US* ga = A + (size_t)(mbase + (tid >> 2)) * NOUTF + (tid & 3) * 8;
  const US* gb = Bt + (size_t)(nbase + (tid >> 2)) * NOUTF + (tid & 3) * 8;
  US* la = As + tid * 8;
  US* lb = Bs + tid * 8;

  for (int kt = 0; kt < NOUTF / 32; ++kt) {
    int ko = kt * 32;
    async16(ga + ko, la);
    async16(ga + ko + (size_t)64 * NOUTF, la + 64 * 32);
    async16(gb + ko, lb);
    __syncthreads();
    short8 a[2], b[4];
#pragma unroll
    for (int i = 0; i < 2; ++i)
      a[i] = *(const short8*)(As + (wave * 32 + i * 16 + lm) * 32 + lk * 8);
#pragma unroll
    for (int j = 0; j < 4; ++j)
      b[j] = *(const short8*)(Bs + (j * 16 + lm) * 32 + lk * 8);
#pragma unroll
    for (int i = 0; i < 2; ++i)
#pragma unroll
      for (int j = 0; j < 4; ++j) acc[i][j] = mfma16(a[i], b[j], acc[i][j]);
    __syncthreads();
  }

#pragma unroll
  for (int j = 0; j < 4; ++j) {
    int col = nbase + j * 16 + lm;
    float bv = bias[col];
#pragma unroll
    for (int i = 0; i < 2; ++i)
#pragma unroll
      for (int r = 0; r < 4; ++r) {
        int row = mbase + wave * 32 + i * 16 + lk * 4 + r;
        out[(size_t)row * NOUTF + col] = acc[i][j][r] + bv;
      }
  }
}

extern "C" void kernel_launch(void* const* d_in, const int* in_sizes, int n_in,
                              void* d_out, int out_size, void* d_ws, size_t ws_size,
                              hipStream_t stream) {
  const float* y    = (const float*)d_in[0];
  const float* Wqkv = (const float*)d_in[1];
  const float* Wff  = (const float*)d_in[2];
  const float* bff  = (const float*)d_in[3];
  float* out = (float*)d_out;

  char* ws = (char*)d_ws;
  US* ybf   = (US*)(ws);                 // [0,8M)  y bf16; dead after qkv
  US* ctx   = (US*)(ws);                 // [0,8M)  reuse for ctx
  US* wqkvt = (US*)(ws + (8u << 20));    // [8,14M)
  US* wfft  = (US*)(ws + (14u << 20));   // [14,16M)
  US* qbuf  = (US*)(ws + (16u << 20));   // [16,24M)
  US* kbuf  = (US*)(ws + (24u << 20));   // [24,32M)
  US* vbuf  = (US*)(ws + (32u << 20));   // [32,40M) dead after vtrans
  US* vtbuf = (US*)(ws + (40u << 20));   // [40,48M)

  k_convert<<<MTOT * NINF / 4 / 256, 256, 0, stream>>>(y, ybf, MTOT * NINF / 4);
  k_wtrans<<<dim3(128, 32), dim3(32, 8), 0, stream>>>(Wqkv, Wff, wqkvt, wfft);
  k_gemm_qkv<<<dim3(N3 / 128, MTOT / 128), 256, 0, stream>>>(ybf, wqkvt, qbuf, kbuf, vbuf);
  k_vtrans<<<dim3(DHEAD / 32, SEQ / 32, BATCH * NHEADS), dim3(32, 8), 0, stream>>>(vbuf, vtbuf);
  k_attn<<<dim3(1024), 256, 0, stream>>>(qbuf, kbuf, vtbuf, ctx);
  k_gemm_out<<<dim3(NOUTF / 64, MTOT / 128), 256, 0, stream>>>(ctx, wfft, bff, out);
}